// Round 16
// baseline (405.723 us; speedup 1.0000x reference)
//
#include <hip/hip_runtime.h>
#include <hip/hip_bf16.h>

// ObjectAttentionBlock on MI355X, round 16.
// r15's swapped-QK^T attn failed: each lane holds only 40/160 keys (key set
// spread over 4 lg-lanes) -> per-lg softmax summed P to 4. Fix: 4-lane-group
// reduce via shfl_xor(16)+shfl_xor(32) for max and sum (4 shuffles vs r12's
// 64 chained). p[] folded into acc in place (-40 VGPR). Rest = r12 skeleton.

typedef __bf16 bf16x8 __attribute__((ext_vector_type(8)));
typedef float f32x4 __attribute__((ext_vector_type(4)));

#define AS1 __attribute__((address_space(1)))
#define AS3 __attribute__((address_space(3)))
#define MFMA_16x16x32(a, b, c) __builtin_amdgcn_mfma_f32_16x16x32_bf16((a), (b), (c), 0, 0, 0)

__device__ __forceinline__ unsigned short f2bf(float f) {
  union { float f; unsigned u; } x; x.f = f;
  unsigned r = (x.u + 0x7FFFu + ((x.u >> 16) & 1u)) >> 16;  // RNE
  return (unsigned short)r;
}

__device__ __forceinline__ unsigned bfpack(float a, float b) {
  return (unsigned)f2bf(a) | ((unsigned)f2bf(b) << 16);
}

// ---------------- key/value kernel + merged weight casts ----------------
__global__ __launch_bounds__(256) void kv_kernel(
    const float* __restrict__ proxy,
    const float* __restrict__ w_fo1, const float* __restrict__ b_fo1,
    const float* __restrict__ w_fo2, const float* __restrict__ b_fo2,
    const float* __restrict__ w_fd, const float* __restrict__ b_fd,
    unsigned short* __restrict__ keyT, unsigned short* __restrict__ Vv,
    const float* __restrict__ w1, const float* __restrict__ w2,
    const float* __restrict__ wu, unsigned short* __restrict__ W1b,
    unsigned short* __restrict__ W2b, unsigned short* __restrict__ Wub) {
  __shared__ float cols[512][8];
  __shared__ float k1s[256][8];
  const int b = blockIdx.y;
  const int p0 = blockIdx.x * 8;      // 20 chunks cover p 0..159
  const int t = threadIdx.x;
  {
    const int base = ((b * 20 + blockIdx.x) * 256 + t) * 8;
#pragma unroll
    for (int i = 0; i < 8; i++) {
      const int idx = base + i;
      if (idx < 131072) W1b[idx] = f2bf(w1[idx]);
      else if (idx < 196608) W2b[idx - 131072] = f2bf(w2[idx - 131072]);
      else Wub[idx - 196608] = f2bf(wu[idx - 196608]);
    }
  }
#pragma unroll
  for (int i = 0; i < 8; i++) {
    int idx = t + i * 256;
    int c = idx >> 2, q = idx & 3;
    int p = p0 + q * 2;
    float2 v = make_float2(0.f, 0.f);
    if (p < 150) v = *(const float2*)(proxy + ((size_t)b * 512 + c) * 150 + p);
    cols[c][q * 2 + 0] = v.x;
    cols[c][q * 2 + 1] = v.y;
  }
  __syncthreads();
  float accV[8], accK[8];
  {
    float bv = b_fd[t], bk = b_fo1[t];
#pragma unroll
    for (int px = 0; px < 8; px++) { accV[px] = bv; accK[px] = bk; }
  }
#define KV_FMA(j, wv_, wk_)                                      \
  { float4 ca = *(const float4*)&cols[c + j][0];                 \
    float4 cb = *(const float4*)&cols[c + j][4];                 \
    accV[0] += wv_ * ca.x; accV[1] += wv_ * ca.y;                \
    accV[2] += wv_ * ca.z; accV[3] += wv_ * ca.w;                \
    accV[4] += wv_ * cb.x; accV[5] += wv_ * cb.y;                \
    accV[6] += wv_ * cb.z; accV[7] += wv_ * cb.w;                \
    accK[0] += wk_ * ca.x; accK[1] += wk_ * ca.y;                \
    accK[2] += wk_ * ca.z; accK[3] += wk_ * ca.w;                \
    accK[4] += wk_ * cb.x; accK[5] += wk_ * cb.y;                \
    accK[6] += wk_ * cb.z; accK[7] += wk_ * cb.w; }
  for (int c = 0; c < 512; c += 4) {
    float4 wv4 = *(const float4*)(w_fd + (size_t)t * 512 + c);
    float4 wk4 = *(const float4*)(w_fo1 + (size_t)t * 512 + c);
    KV_FMA(0, wv4.x, wk4.x)
    KV_FMA(1, wv4.y, wk4.y)
    KV_FMA(2, wv4.z, wk4.z)
    KV_FMA(3, wv4.w, wk4.w)
  }
#pragma unroll
  for (int px = 0; px < 8; px++) {
    Vv[((size_t)b * 256 + t) * 160 + p0 + px] = f2bf(fmaxf(accV[px], 0.f));
    k1s[t][px] = fmaxf(accK[px], 0.f);
  }
  __syncthreads();
  float accY[8];
  {
    float by = b_fo2[t];
#pragma unroll
    for (int px = 0; px < 8; px++) accY[px] = by;
  }
#define KV_FMA2(j, wy_)                                          \
  { float4 ca = *(const float4*)&k1s[c + j][0];                  \
    float4 cb = *(const float4*)&k1s[c + j][4];                  \
    accY[0] += wy_ * ca.x; accY[1] += wy_ * ca.y;                \
    accY[2] += wy_ * ca.z; accY[3] += wy_ * ca.w;                \
    accY[4] += wy_ * cb.x; accY[5] += wy_ * cb.y;                \
    accY[6] += wy_ * cb.z; accY[7] += wy_ * cb.w; }
  for (int c = 0; c < 256; c += 4) {
    float4 wy4 = *(const float4*)(w_fo2 + (size_t)t * 256 + c);
    KV_FMA2(0, wy4.x)
    KV_FMA2(1, wy4.y)
    KV_FMA2(2, wy4.z)
    KV_FMA2(3, wy4.w)
  }
#pragma unroll
  for (int px = 0; px < 8; px++)
    keyT[((size_t)b * 160 + p0 + px) * 256 + t] = f2bf(fmaxf(accY[px], 0.f));
}

// ---------------- GEMM1 fused transpose: q1T = relu(x^T @ W1^T + b1) ----------------
__global__ __launch_bounds__(256, 3) void gemm1_fused(
    const float* __restrict__ X, const unsigned short* __restrict__ Bt,
    const float* __restrict__ bias, unsigned short* __restrict__ Cq) {
  const int HW = 16384, K = 512, N = 256;
  __shared__ float Af[64 * 128];
  __shared__ unsigned short Bs[128 * 64];
  const int r = blockIdx.x;                 // 0..255
  const int b = blockIdx.y;
  const int my = ((r >> 4) << 3) | (r & 7); // 0..127
  const int nx = (r >> 3) & 1;
  const int m0 = my * 128, n0 = nx * 128;
  const int tid = threadIdx.x;
  const int w = tid >> 6, l = tid & 63;
  const int lr = l & 15, lg = l >> 4;
  const int wm = (w >> 1) * 64, wn = (w & 1) * 64;
  const float* Xb = X + (size_t)b * K * HW;
  const unsigned short* Btb = Bt + (size_t)n0 * K;
  const f32x4 zero = {0.f, 0.f, 0.f, 0.f};
  f32x4 acc[4][4];
#pragma unroll
  for (int m = 0; m < 4; m++)
#pragma unroll
    for (int n = 0; n < 4; n++) acc[m][n] = zero;

  const int arow = l >> 5, acol = l & 31;
  const int bsub = l >> 3, bcol = (l & 7) * 8;
  for (int kt = 0; kt < K; kt += 64) {
    __syncthreads();
#pragma unroll
    for (int i = 0; i < 8; i++) {
      const int rk = w * 16 + i * 2 + arow;
      const int s = (rk >> 3) & 7;
      __builtin_amdgcn_global_load_lds(
          (AS1 void*)(Xb + (size_t)(kt + rk) * HW + m0 + ((acol ^ s) << 2)),
          (AS3 void*)(Af + (w * 16 + i * 2) * 128), 16, 0, 0);
    }
#pragma unroll
    for (int i = 0; i < 4; i++) {
      __builtin_amdgcn_global_load_lds(
          (AS1 void*)(Btb + (size_t)(w * 32 + i * 8 + bsub) * K + kt + bcol),
          (AS3 void*)(Bs + (w * 32 + i * 8) * 64), 16, 0, 0);
    }
    __syncthreads();
#pragma unroll
    for (int ks = 0; ks < 2; ks++) {
      bf16x8 aF[4], bF[4];
      const int s = ks * 4 + lg;
#pragma unroll
      for (int m = 0; m < 4; m++) {
        const int p = wm + m * 16 + lr;
        const int cb = ((((p >> 2) ^ s) << 2) | (p & 3));
        bf16x8 a;
#pragma unroll
        for (int j = 0; j < 8; j++)
          a[j] = (__bf16)Af[(ks * 32 + lg * 8 + j) * 128 + cb];
        aF[m] = a;
      }
#pragma unroll
      for (int n = 0; n < 4; n++)
        bF[n] = *(const bf16x8*)(Bs + (wn + n * 16 + lr) * 64 + ks * 32 + lg * 8);
#pragma unroll
      for (int m = 0; m < 4; m++)
#pragma unroll
        for (int n = 0; n < 4; n++) acc[m][n] = MFMA_16x16x32(aF[m], bF[n], acc[m][n]);
    }
  }
  unsigned short* Cb = Cq + (size_t)b * HW * N;
#pragma unroll
  for (int m = 0; m < 4; m++) {
#pragma unroll
    for (int n = 0; n < 4; n++) {
      const int col = n0 + wn + n * 16 + lr;
      const float bc = bias[col];
#pragma unroll
      for (int r2 = 0; r2 < 4; r2++) {
        const int row = m0 + wm + m * 16 + lg * 4 + r2;
        Cb[(size_t)row * N + col] = f2bf(fmaxf(acc[m][n][r2] + bc, 0.f));
      }
    }
  }
}

// ---------------- generic bf16 GEMM: C = relu(A @ Bt^T + bias), K=KC ----------------
template <int BIAS_ROW, int OUTF32, int COLOC, int KC>
__global__ __launch_bounds__(256, 4) void gemm_bt_relu(
    const unsigned short* __restrict__ A, const unsigned short* __restrict__ Bt,
    const float* __restrict__ bias, void* __restrict__ Cout,
    int M, int N, long long sA, long long sB, long long sC) {
  __shared__ unsigned short As[128 * 64];
  __shared__ unsigned short Bs[128 * 64];
  int m0, n0, b;
  if (COLOC == 1) {            // M=16384 (128 tiles), N=256 (2 tiles), B=8
    const int g = blockIdx.x, x = g & 7, j = g >> 3;
    const int og = ((j >> 1) << 3) | x;      // (pix,b) id, 0..1023
    n0 = (j & 1) * 128; m0 = (og & 127) * 128; b = og >> 7;
  } else if (COLOC == 2) {     // M=512 (4 tiles), N=16384 (128 tiles), B=8
    const int g = blockIdx.x, x = g & 7, j = g >> 3;
    const int og = ((j >> 2) << 3) | x;
    m0 = (j & 3) * 128; n0 = (og & 127) * 128; b = og >> 7;
  } else {
    b = blockIdx.z; m0 = blockIdx.x * 128; n0 = blockIdx.y * 128;
  }
  const int tid = threadIdx.x;
  const int w = tid >> 6, l = tid & 63;
  const int lr = l & 15, lg = l >> 4;
  const int wm = (w >> 1) * 64, wn = (w & 1) * 64;
  const unsigned short* Ab = A + (size_t)b * sA + (size_t)m0 * KC;
  const unsigned short* Btb = Bt + (size_t)b * sB + (size_t)n0 * KC;
  const f32x4 zero = {0.f, 0.f, 0.f, 0.f};
  f32x4 acc[4][4];
#pragma unroll
  for (int m = 0; m < 4; m++)
#pragma unroll
    for (int n = 0; n < 4; n++) acc[m][n] = zero;

  const int srow = w * 32 + (l >> 3);
  const int scol = (l & 7) * 8;
#pragma unroll
  for (int kt = 0; kt < KC; kt += 64) {
    __syncthreads();
#pragma unroll
    for (int i = 0; i < 4; i++) {
      __builtin_amdgcn_global_load_lds(
          (AS1 void*)(Ab + (size_t)(srow + i * 8) * KC + kt + scol),
          (AS3 void*)(As + (w * 32 + i * 8) * 64), 16, 0, 0);
      __builtin_amdgcn_global_load_lds(
          (AS1 void*)(Btb + (size_t)(srow + i * 8) * KC + kt + scol),
          (AS3 void*)(Bs + (w * 32 + i * 8) * 64), 16, 0, 0);
    }
    __syncthreads();
#pragma unroll
    for (int ks = 0; ks < 2; ks++) {
      bf16x8 aF[4], bF[4];
#pragma unroll
      for (int m = 0; m < 4; m++)
        aF[m] = *(const bf16x8*)(As + (wm + m * 16 + lr) * 64 + ks * 32 + lg * 8);
#pragma unroll
      for (int n = 0; n < 4; n++)
        bF[n] = *(const bf16x8*)(Bs + (wn + n * 16 + lr) * 64 + ks * 32 + lg * 8);
#pragma unroll
      for (int m = 0; m < 4; m++)
#pragma unroll
        for (int n = 0; n < 4; n++) acc[m][n] = MFMA_16x16x32(aF[m], bF[n], acc[m][n]);
    }
  }
#pragma unroll
  for (int m = 0; m < 4; m++) {
#pragma unroll
    for (int n = 0; n < 4; n++) {
      const int col = n0 + wn + n * 16 + lr;
      const float bc = BIAS_ROW ? 0.f : bias[col];
#pragma unroll
      for (int r = 0; r < 4; r++) {
        const int row = m0 + wm + m * 16 + lg * 4 + r;
        float v = acc[m][n][r] + (BIAS_ROW ? bias[row] : bc);
        v = fmaxf(v, 0.f);
        if (OUTF32)
          ((float*)Cout)[(size_t)b * sC + (size_t)row * N + col] = v;
        else
          ((unsigned short*)Cout)[(size_t)b * sC + (size_t)row * N + col] = f2bf(v);
      }
    }
  }
}

// ---------------- fused attention v2: swapped QK^T, 4-shuffle softmax ----------------
// Wave handles 16 pixels. S^T = mfma(K, q2): lane (lr,lg) holds S[k][pix lr]
// for k = n*16 + lg*4 + r (40 of 160; key set spans the 4 lg-lanes). Softmax
// reduce = shfl_xor(16)+shfl_xor(32) for max and sum (4 shuffles total).
// P redistributed to PV B-frags via independent shuffles; PV = mfma(V, P) ->
// ctx[ch][pix]; output coalesced via wave-private XOR-swizzled LDS tile.
__global__ __launch_bounds__(256, 4) void attn_kernel(
    const unsigned short* __restrict__ Q, const unsigned short* __restrict__ Kt,
    const unsigned short* __restrict__ Vv, unsigned short* __restrict__ ctxT) {
  const int HW = 16384;
  __shared__ __align__(16) char ctx_lds[65 * 512];  // 64 pix x 512B (+pad row)
  const int b = blockIdx.y;
  const int pix0 = blockIdx.x * 64;
  const int tid = (int)threadIdx.x;
  const int w = tid >> 6, l = tid & 63;
  const int lr = l & 15, lg = (l >> 4) & 3;
  const int pixb = pix0 + w * 16;
  const unsigned short* Qb = Q + ((size_t)b * HW + pixb) * 256;
  const unsigned short* Kb = Kt + (size_t)b * 160 * 256;
  const unsigned short* Vb = Vv + (size_t)b * 256 * 160;
  const f32x4 zero = {0.f, 0.f, 0.f, 0.f};

  // S^T = K @ q2^T : acc[n][r] = S[key=n*16+lg*4+r][pixel=pixb+lr]
  f32x4 acc[10];
#pragma unroll
  for (int n = 0; n < 10; n++) acc[n] = zero;
#pragma unroll 2
  for (int ks = 0; ks < 8; ks++) {
    bf16x8 bQ = *(const bf16x8*)(Qb + (size_t)lr * 256 + ks * 32 + lg * 8);
    __builtin_amdgcn_s_setprio(1);
#pragma unroll
    for (int n = 0; n < 10; n++) {
      bf16x8 aK = *(const bf16x8*)(Kb + (size_t)(n * 16 + lr) * 256 + ks * 32 + lg * 8);
      acc[n] = MFMA_16x16x32(aK, bQ, acc[n]);
    }
    __builtin_amdgcn_s_setprio(0);
  }
  // softmax over k = n*16 + lg*4 + r, mask k >= 150. Key set for pixel lr is
  // spread over the 4 lg-lanes -> reduce across lanes l^16, l^32.
  const float scale = 0.0625f;  // 1/sqrt(256)
  const int kof = lg << 2;
  float mx = -1e30f;
#pragma unroll
  for (int n = 0; n < 10; n++)
#pragma unroll
    for (int r = 0; r < 4; r++) {
      float v = acc[n][r] * scale;
      v = (n * 16 + kof + r < 150) ? v : -1e30f;
      acc[n][r] = v;
      mx = fmaxf(mx, v);
    }
  mx = fmaxf(mx, __shfl_xor(mx, 16, 64));
  mx = fmaxf(mx, __shfl_xor(mx, 32, 64));
  float s = 0.f;
#pragma unroll
  for (int n = 0; n < 10; n++)
#pragma unroll
    for (int r = 0; r < 4; r++) {
      float e = __expf(acc[n][r] - mx);  // masked -> exp(-huge) = 0
      acc[n][r] = e;
      s += e;
    }
  s += __shfl_xor(s, 16, 64);
  s += __shfl_xor(s, 32, 64);
  const float inv = 1.f / s;
  unsigned d0[10], d1[10];
#pragma unroll
  for (int n = 0; n < 10; n++) {
    d0[n] = bfpack(acc[n][0] * inv, acc[n][1] * inv);
    d1[n] = bfpack(acc[n][2] * inv, acc[n][3] * inv);
  }
  // redistribute: PV B-frag lane (lr,lg) word q holds P[pix lr][k=k2*32+lg*8+2q(+1)]
  // source lane lg' = 2*(lg&1)+(q>>1), register n = 2*k2+(lg>>1), d0/d1 by q parity.
  const int srcA = lr + ((lg & 1) << 5);   // lg' = 2*(lg&1)
  const int srcB = srcA + 16;              // lg' + 1
  const bool hi = (lg >> 1) != 0;
  uint4 wv[5];
#pragma unroll
  for (int k2 = 0; k2 < 5; k2++) {
    unsigned e0 = (unsigned)__shfl((int)d0[2 * k2], srcA);
    unsigned e1 = (unsigned)__shfl((int)d1[2 * k2], srcA);
    unsigned e2 = (unsigned)__shfl((int)d0[2 * k2], srcB);
    unsigned e3 = (unsigned)__shfl((int)d1[2 * k2], srcB);
    unsigned o0 = (unsigned)__shfl((int)d0[2 * k2 + 1], srcA);
    unsigned o1 = (unsigned)__shfl((int)d1[2 * k2 + 1], srcA);
    unsigned o2 = (unsigned)__shfl((int)d0[2 * k2 + 1], srcB);
    unsigned o3 = (unsigned)__shfl((int)d1[2 * k2 + 1], srcB);
    wv[k2].x = hi ? o0 : e0;
    wv[k2].y = hi ? o1 : e1;
    wv[k2].z = hi ? o2 : e2;
    wv[k2].w = hi ? o3 : e3;
  }
  // PV: ctx[ch][pix] = sum_k V[ch][k] P[pix][k], two ch-halves
  const int pixL = w * 16 + lr;
  const unsigned swz = ((unsigned)pixL & 7u) << 4;
#pragma unroll
  for (int half = 0; half < 2; half++) {
    f32x4 acc2[8];
#pragma unroll
    for (int m = 0; m < 8; m++) acc2[m] = zero;
#pragma unroll
    for (int k2 = 0; k2 < 5; k2++) {
      union { uint4 u; bf16x8 h; } cvt; cvt.u = wv[k2];
      const bf16x8 bP = cvt.h;
      __builtin_amdgcn_s_setprio(1);
#pragma unroll
      for (int m = 0; m < 8; m++) {
        bf16x8 aV = *(const bf16x8*)(Vb + (size_t)(half * 128 + m * 16 + lr) * 160 +
                                     k2 * 32 + lg * 8);
        acc2[m] = MFMA_16x16x32(aV, bP, acc2[m]);
      }
      __builtin_amdgcn_s_setprio(0);
    }
    // lane (lr,lg) writes ch = half*128 + m*16 + lg*4 + (0..3) of pixel pixL
#pragma unroll
    for (int m = 0; m < 8; m++) {
      uint2 v;
      v.x = bfpack(acc2[m][0], acc2[m][1]);
      v.y = bfpack(acc2[m][2], acc2[m][3]);
      const unsigned boff =
          ((unsigned)pixL * 512 + (unsigned)(half * 128 + m * 16 + lg * 4) * 2) ^ swz;
      *(uint2*)(ctx_lds + boff) = v;
    }
  }
  // wave-private: same wave wrote pixels w*16..w*16+15; drain LDS then store
  asm volatile("s_waitcnt lgkmcnt(0)" ::: "memory");
  __builtin_amdgcn_sched_barrier(0);
  {
    const int prow = w * 16 + (l >> 2);     // this wave's own pixels
    const int chunk = l & 3;                // 128B chunk of the 512B row
    unsigned short* Ob = ctxT + ((size_t)b * HW + pix0 + prow) * 256 + chunk * 64;
    const unsigned rswz = ((unsigned)prow & 7u) << 4;
#pragma unroll
    for (int i = 0; i < 8; i++) {
      const unsigned boff = ((unsigned)prow * 512 + (unsigned)chunk * 128 + i * 16) ^ rswz;
      uint4 v = *(const uint4*)(ctx_lds + boff);
      *(uint4*)(Ob + i * 8) = v;
    }
  }
}

// ---------------- host launcher ----------------
extern "C" void kernel_launch(void* const* d_in, const int* in_sizes, int n_in,
                              void* d_out, int out_size, void* d_ws, size_t ws_size,
                              hipStream_t stream) {
  (void)in_sizes; (void)n_in; (void)out_size;
  const float* x     = (const float*)d_in[0];
  const float* proxy = (const float*)d_in[1];
  const float* w_fp1 = (const float*)d_in[2];
  const float* b_fp1 = (const float*)d_in[3];
  const float* w_fp2 = (const float*)d_in[4];
  const float* b_fp2 = (const float*)d_in[5];
  const float* w_fo1 = (const float*)d_in[6];
  const float* b_fo1 = (const float*)d_in[7];
  const float* w_fo2 = (const float*)d_in[8];
  const float* b_fo2 = (const float*)d_in[9];
  const float* w_fd  = (const float*)d_in[10];
  const float* b_fd  = (const float*)d_in[11];
  const float* w_fu  = (const float*)d_in[12];
  const float* b_fu  = (const float*)d_in[13];

  char* ws = (char*)d_ws;
  unsigned short* W1b  = (unsigned short*)(ws + 0);          // 256x512 bf16
  unsigned short* W2b  = (unsigned short*)(ws + 262144);     // 256x256
  unsigned short* Wub  = (unsigned short*)(ws + 393216);     // 512x256
  unsigned short* keyT = (unsigned short*)(ws + 655360);     // [8][160][256]
  unsigned short* Vv   = (unsigned short*)(ws + 1310720);    // [8][256][160]
  unsigned short* bufA = (unsigned short*)(ws + 2097152);    // q2T
  unsigned short* bufB = (unsigned short*)(ws + 2097152 + 134217728);  // q1T, later ctxT
  if (ws_size < 203423744) return;

  dim3 blk(256);
  kv_kernel<<<dim3(20, 8), blk, 0, stream>>>(proxy, w_fo1, b_fo1, w_fo2, b_fo2,
                                             w_fd, b_fd, keyT, Vv,
                                             w_fp1, w_fp2, w_fu, W1b, W2b, Wub);
  gemm1_fused<<<dim3(256, 8), blk, 0, stream>>>(x, W1b, b_fp1, bufB);
  gemm_bt_relu<0, 0, 1, 256><<<2048, blk, 0, stream>>>(
      bufB, W2b, b_fp2, bufA, 16384, 256,
      (long long)16384 * 256, 0, (long long)16384 * 256);
  attn_kernel<<<dim3(256, 8), blk, 0, stream>>>(bufA, keyT, Vv, bufB);
  gemm_bt_relu<1, 1, 2, 256><<<4096, blk, 0, stream>>>(
      Wub, bufB, b_fu, d_out, 512, 16384,
      0, (long long)16384 * 256, (long long)512 * 16384);
}

// Round 17
// 357.755 us; speedup vs baseline: 1.1341x; 1.1341x over previous
//
#include <hip/hip_runtime.h>
#include <hip/hip_bf16.h>

// ObjectAttentionBlock on MI355X, round 17 = exact r12 restore (360.5us best).
// r13-r16 experiments (sync reg-staging, G_up store swap, swapped-QK^T attn
// x2) all regressed or failed; r12 is the confirmed local optimum. Skeleton:
// kv+casts -> gemm1(fused transpose, async f32 stage) -> G2(XCD coloc, KC) ->
// attn(barrier-free wave-private P + setprio) -> G_up(XCD coloc, KC).

typedef __bf16 bf16x8 __attribute__((ext_vector_type(8)));
typedef float f32x4 __attribute__((ext_vector_type(4)));

#define AS1 __attribute__((address_space(1)))
#define AS3 __attribute__((address_space(3)))
#define MFMA_16x16x32(a, b, c) __builtin_amdgcn_mfma_f32_16x16x32_bf16((a), (b), (c), 0, 0, 0)

__device__ __forceinline__ unsigned short f2bf(float f) {
  union { float f; unsigned u; } x; x.f = f;
  unsigned r = (x.u + 0x7FFFu + ((x.u >> 16) & 1u)) >> 16;  // RNE
  return (unsigned short)r;
}

// ---------------- key/value kernel + merged weight casts ----------------
__global__ __launch_bounds__(256) void kv_kernel(
    const float* __restrict__ proxy,
    const float* __restrict__ w_fo1, const float* __restrict__ b_fo1,
    const float* __restrict__ w_fo2, const float* __restrict__ b_fo2,
    const float* __restrict__ w_fd, const float* __restrict__ b_fd,
    unsigned short* __restrict__ keyT, unsigned short* __restrict__ Vv,
    const float* __restrict__ w1, const float* __restrict__ w2,
    const float* __restrict__ wu, unsigned short* __restrict__ W1b,
    unsigned short* __restrict__ W2b, unsigned short* __restrict__ Wub) {
  __shared__ float cols[512][8];
  __shared__ float k1s[256][8];
  const int b = blockIdx.y;
  const int p0 = blockIdx.x * 8;      // 20 chunks cover p 0..159
  const int t = threadIdx.x;
  // ---- merged weight casts: 160 blocks x 256 thr x 8 = 327680 items exact
  {
    const int base = ((b * 20 + blockIdx.x) * 256 + t) * 8;
#pragma unroll
    for (int i = 0; i < 8; i++) {
      const int idx = base + i;
      if (idx < 131072) W1b[idx] = f2bf(w1[idx]);
      else if (idx < 196608) W2b[idx - 131072] = f2bf(w2[idx - 131072]);
      else Wub[idx - 196608] = f2bf(wu[idx - 196608]);
    }
  }
#pragma unroll
  for (int i = 0; i < 8; i++) {
    int idx = t + i * 256;
    int c = idx >> 2, q = idx & 3;
    int p = p0 + q * 2;
    float2 v = make_float2(0.f, 0.f);
    if (p < 150) v = *(const float2*)(proxy + ((size_t)b * 512 + c) * 150 + p);
    cols[c][q * 2 + 0] = v.x;
    cols[c][q * 2 + 1] = v.y;
  }
  __syncthreads();
  float accV[8], accK[8];
  {
    float bv = b_fd[t], bk = b_fo1[t];
#pragma unroll
    for (int px = 0; px < 8; px++) { accV[px] = bv; accK[px] = bk; }
  }
#define KV_FMA(j, wv_, wk_)                                      \
  { float4 ca = *(const float4*)&cols[c + j][0];                 \
    float4 cb = *(const float4*)&cols[c + j][4];                 \
    accV[0] += wv_ * ca.x; accV[1] += wv_ * ca.y;                \
    accV[2] += wv_ * ca.z; accV[3] += wv_ * ca.w;                \
    accV[4] += wv_ * cb.x; accV[5] += wv_ * cb.y;                \
    accV[6] += wv_ * cb.z; accV[7] += wv_ * cb.w;                \
    accK[0] += wk_ * ca.x; accK[1] += wk_ * ca.y;                \
    accK[2] += wk_ * ca.z; accK[3] += wk_ * ca.w;                \
    accK[4] += wk_ * cb.x; accK[5] += wk_ * cb.y;                \
    accK[6] += wk_ * cb.z; accK[7] += wk_ * cb.w; }
  for (int c = 0; c < 512; c += 4) {
    float4 wv4 = *(const float4*)(w_fd + (size_t)t * 512 + c);
    float4 wk4 = *(const float4*)(w_fo1 + (size_t)t * 512 + c);
    KV_FMA(0, wv4.x, wk4.x)
    KV_FMA(1, wv4.y, wk4.y)
    KV_FMA(2, wv4.z, wk4.z)
    KV_FMA(3, wv4.w, wk4.w)
  }
#pragma unroll
  for (int px = 0; px < 8; px++) {
    Vv[((size_t)b * 256 + t) * 160 + p0 + px] = f2bf(fmaxf(accV[px], 0.f));
    k1s[t][px] = fmaxf(accK[px], 0.f);
  }
  __syncthreads();
  float accY[8];
  {
    float by = b_fo2[t];
#pragma unroll
    for (int px = 0; px < 8; px++) accY[px] = by;
  }
#define KV_FMA2(j, wy_)                                          \
  { float4 ca = *(const float4*)&k1s[c + j][0];                  \
    float4 cb = *(const float4*)&k1s[c + j][4];                  \
    accY[0] += wy_ * ca.x; accY[1] += wy_ * ca.y;                \
    accY[2] += wy_ * ca.z; accY[3] += wy_ * ca.w;                \
    accY[4] += wy_ * cb.x; accY[5] += wy_ * cb.y;                \
    accY[6] += wy_ * cb.z; accY[7] += wy_ * cb.w; }
  for (int c = 0; c < 256; c += 4) {
    float4 wy4 = *(const float4*)(w_fo2 + (size_t)t * 256 + c);
    KV_FMA2(0, wy4.x)
    KV_FMA2(1, wy4.y)
    KV_FMA2(2, wy4.z)
    KV_FMA2(3, wy4.w)
  }
#pragma unroll
  for (int px = 0; px < 8; px++)
    keyT[((size_t)b * 160 + p0 + px) * 256 + t] = f2bf(fmaxf(accY[px], 0.f));
}

// ---------------- GEMM1 fused transpose: q1T = relu(x^T @ W1^T + b1) ----------------
__global__ __launch_bounds__(256, 3) void gemm1_fused(
    const float* __restrict__ X, const unsigned short* __restrict__ Bt,
    const float* __restrict__ bias, unsigned short* __restrict__ Cq) {
  const int HW = 16384, K = 512, N = 256;
  __shared__ float Af[64 * 128];
  __shared__ unsigned short Bs[128 * 64];
  const int r = blockIdx.x;                 // 0..255
  const int b = blockIdx.y;
  const int my = ((r >> 4) << 3) | (r & 7); // 0..127
  const int nx = (r >> 3) & 1;
  const int m0 = my * 128, n0 = nx * 128;
  const int tid = threadIdx.x;
  const int w = tid >> 6, l = tid & 63;
  const int lr = l & 15, lg = l >> 4;
  const int wm = (w >> 1) * 64, wn = (w & 1) * 64;
  const float* Xb = X + (size_t)b * K * HW;
  const unsigned short* Btb = Bt + (size_t)n0 * K;
  const f32x4 zero = {0.f, 0.f, 0.f, 0.f};
  f32x4 acc[4][4];
#pragma unroll
  for (int m = 0; m < 4; m++)
#pragma unroll
    for (int n = 0; n < 4; n++) acc[m][n] = zero;

  const int arow = l >> 5, acol = l & 31;
  const int bsub = l >> 3, bcol = (l & 7) * 8;
  for (int kt = 0; kt < K; kt += 64) {
    __syncthreads();
#pragma unroll
    for (int i = 0; i < 8; i++) {
      const int rk = w * 16 + i * 2 + arow;
      const int s = (rk >> 3) & 7;
      __builtin_amdgcn_global_load_lds(
          (AS1 void*)(Xb + (size_t)(kt + rk) * HW + m0 + ((acol ^ s) << 2)),
          (AS3 void*)(Af + (w * 16 + i * 2) * 128), 16, 0, 0);
    }
#pragma unroll
    for (int i = 0; i < 4; i++) {
      __builtin_amdgcn_global_load_lds(
          (AS1 void*)(Btb + (size_t)(w * 32 + i * 8 + bsub) * K + kt + bcol),
          (AS3 void*)(Bs + (w * 32 + i * 8) * 64), 16, 0, 0);
    }
    __syncthreads();
#pragma unroll
    for (int ks = 0; ks < 2; ks++) {
      bf16x8 aF[4], bF[4];
      const int s = ks * 4 + lg;
#pragma unroll
      for (int m = 0; m < 4; m++) {
        const int p = wm + m * 16 + lr;
        const int cb = ((((p >> 2) ^ s) << 2) | (p & 3));
        bf16x8 a;
#pragma unroll
        for (int j = 0; j < 8; j++)
          a[j] = (__bf16)Af[(ks * 32 + lg * 8 + j) * 128 + cb];
        aF[m] = a;
      }
#pragma unroll
      for (int n = 0; n < 4; n++)
        bF[n] = *(const bf16x8*)(Bs + (wn + n * 16 + lr) * 64 + ks * 32 + lg * 8);
#pragma unroll
      for (int m = 0; m < 4; m++)
#pragma unroll
        for (int n = 0; n < 4; n++) acc[m][n] = MFMA_16x16x32(aF[m], bF[n], acc[m][n]);
    }
  }
  unsigned short* Cb = Cq + (size_t)b * HW * N;
#pragma unroll
  for (int m = 0; m < 4; m++) {
#pragma unroll
    for (int n = 0; n < 4; n++) {
      const int col = n0 + wn + n * 16 + lr;
      const float bc = bias[col];
#pragma unroll
      for (int r2 = 0; r2 < 4; r2++) {
        const int row = m0 + wm + m * 16 + lg * 4 + r2;
        Cb[(size_t)row * N + col] = f2bf(fmaxf(acc[m][n][r2] + bc, 0.f));
      }
    }
  }
}

// ---------------- generic bf16 GEMM: C = relu(A @ Bt^T + bias), K=KC ----------------
template <int BIAS_ROW, int OUTF32, int COLOC, int KC>
__global__ __launch_bounds__(256, 4) void gemm_bt_relu(
    const unsigned short* __restrict__ A, const unsigned short* __restrict__ Bt,
    const float* __restrict__ bias, void* __restrict__ Cout,
    int M, int N, long long sA, long long sB, long long sC) {
  __shared__ unsigned short As[128 * 64];
  __shared__ unsigned short Bs[128 * 64];
  int m0, n0, b;
  if (COLOC == 1) {            // M=16384 (128 tiles), N=256 (2 tiles), B=8
    const int g = blockIdx.x, x = g & 7, j = g >> 3;
    const int og = ((j >> 1) << 3) | x;      // (pix,b) id, 0..1023
    n0 = (j & 1) * 128; m0 = (og & 127) * 128; b = og >> 7;
  } else if (COLOC == 2) {     // M=512 (4 tiles), N=16384 (128 tiles), B=8
    const int g = blockIdx.x, x = g & 7, j = g >> 3;
    const int og = ((j >> 2) << 3) | x;
    m0 = (j & 3) * 128; n0 = (og & 127) * 128; b = og >> 7;
  } else {
    b = blockIdx.z; m0 = blockIdx.x * 128; n0 = blockIdx.y * 128;
  }
  const int tid = threadIdx.x;
  const int w = tid >> 6, l = tid & 63;
  const int lr = l & 15, lg = l >> 4;
  const int wm = (w >> 1) * 64, wn = (w & 1) * 64;
  const unsigned short* Ab = A + (size_t)b * sA + (size_t)m0 * KC;
  const unsigned short* Btb = Bt + (size_t)b * sB + (size_t)n0 * KC;
  const f32x4 zero = {0.f, 0.f, 0.f, 0.f};
  f32x4 acc[4][4];
#pragma unroll
  for (int m = 0; m < 4; m++)
#pragma unroll
    for (int n = 0; n < 4; n++) acc[m][n] = zero;

  const int srow = w * 32 + (l >> 3);
  const int scol = (l & 7) * 8;
#pragma unroll
  for (int kt = 0; kt < KC; kt += 64) {
    __syncthreads();
#pragma unroll
    for (int i = 0; i < 4; i++) {
      __builtin_amdgcn_global_load_lds(
          (AS1 void*)(Ab + (size_t)(srow + i * 8) * KC + kt + scol),
          (AS3 void*)(As + (w * 32 + i * 8) * 64), 16, 0, 0);
      __builtin_amdgcn_global_load_lds(
          (AS1 void*)(Btb + (size_t)(srow + i * 8) * KC + kt + scol),
          (AS3 void*)(Bs + (w * 32 + i * 8) * 64), 16, 0, 0);
    }
    __syncthreads();
#pragma unroll
    for (int ks = 0; ks < 2; ks++) {
      bf16x8 aF[4], bF[4];
#pragma unroll
      for (int m = 0; m < 4; m++)
        aF[m] = *(const bf16x8*)(As + (wm + m * 16 + lr) * 64 + ks * 32 + lg * 8);
#pragma unroll
      for (int n = 0; n < 4; n++)
        bF[n] = *(const bf16x8*)(Bs + (wn + n * 16 + lr) * 64 + ks * 32 + lg * 8);
#pragma unroll
      for (int m = 0; m < 4; m++)
#pragma unroll
        for (int n = 0; n < 4; n++) acc[m][n] = MFMA_16x16x32(aF[m], bF[n], acc[m][n]);
    }
  }
#pragma unroll
  for (int m = 0; m < 4; m++) {
#pragma unroll
    for (int n = 0; n < 4; n++) {
      const int col = n0 + wn + n * 16 + lr;
      const float bc = BIAS_ROW ? 0.f : bias[col];
#pragma unroll
      for (int r = 0; r < 4; r++) {
        const int row = m0 + wm + m * 16 + lg * 4 + r;
        float v = acc[m][n][r] + (BIAS_ROW ? bias[row] : bc);
        v = fmaxf(v, 0.f);
        if (OUTF32)
          ((float*)Cout)[(size_t)b * sC + (size_t)row * N + col] = v;
        else
          ((unsigned short*)Cout)[(size_t)b * sC + (size_t)row * N + col] = f2bf(v);
      }
    }
  }
}

// ---------------- fused attention: ctxT = softmax(Q Kt^T /16) @ V ----------------
// NO inter-wave barrier: P rows are wave-private (wave w touches only rows
// w*32..w*32+31); same-wave LDS write->read ordering via lgkmcnt. setprio(1)
// wraps MFMA clusters (pays now that waves phase-diverge).
__global__ __launch_bounds__(256, 4) void attn_kernel(
    const unsigned short* __restrict__ Q, const unsigned short* __restrict__ Kt,
    const unsigned short* __restrict__ Vv, unsigned short* __restrict__ ctxT) {
  const int HW = 16384;
  __shared__ unsigned short Pls[128 * 160];
  const int b = blockIdx.y;
  const int pix0 = blockIdx.x * 128;
  const int tid = threadIdx.x;
  const int w = tid >> 6, l = tid & 63;
  const int lr = l & 15, lg = l >> 4;
  const unsigned short* Qb = Q + ((size_t)b * HW + pix0 + w * 32) * 256;
  const unsigned short* Kb = Kt + (size_t)b * 160 * 256;
  const unsigned short* Vb = Vv + (size_t)b * 256 * 160;
  const f32x4 zero = {0.f, 0.f, 0.f, 0.f};

  f32x4 acc[2][10];
#pragma unroll
  for (int m = 0; m < 2; m++)
#pragma unroll
    for (int n = 0; n < 10; n++) acc[m][n] = zero;
#pragma unroll 2
  for (int ks = 0; ks < 8; ks++) {
    bf16x8 aF[2];
#pragma unroll
    for (int m = 0; m < 2; m++)
      aF[m] = *(const bf16x8*)(Qb + (size_t)(m * 16 + lr) * 256 + ks * 32 + lg * 8);
    __builtin_amdgcn_s_setprio(1);
#pragma unroll
    for (int n = 0; n < 10; n++) {
      bf16x8 bF = *(const bf16x8*)(Kb + (size_t)(n * 16 + lr) * 256 + ks * 32 + lg * 8);
      acc[0][n] = MFMA_16x16x32(aF[0], bF, acc[0][n]);
      acc[1][n] = MFMA_16x16x32(aF[1], bF, acc[1][n]);
    }
    __builtin_amdgcn_s_setprio(0);
  }
  const float scale = 0.0625f;  // 1/sqrt(256)
#pragma unroll
  for (int m = 0; m < 2; m++) {
#pragma unroll
    for (int r = 0; r < 4; r++) {
      float lm = -1e30f;
#pragma unroll
      for (int n = 0; n < 10; n++) {
        float v = acc[m][n][r] * scale;
        acc[m][n][r] = v;
        if (n * 16 + lr < 150) lm = fmaxf(lm, v);
      }
#pragma unroll
      for (int msk = 1; msk <= 8; msk <<= 1) lm = fmaxf(lm, __shfl_xor(lm, msk, 64));
      float s = 0.f;
#pragma unroll
      for (int n = 0; n < 10; n++) {
        float p = (n * 16 + lr < 150) ? __expf(acc[m][n][r] - lm) : 0.f;
        acc[m][n][r] = p;
        s += p;
      }
#pragma unroll
      for (int msk = 1; msk <= 8; msk <<= 1) s += __shfl_xor(s, msk, 64);
      float inv = 1.f / s;
      const int row = w * 32 + m * 16 + lg * 4 + r;
      const unsigned sw = (unsigned)(row & 7) << 4;
#pragma unroll
      for (int n = 0; n < 10; n++) {
        unsigned boff = (unsigned)row * 320 + (unsigned)(n * 16 + lr) * 2;
        *(unsigned short*)((char*)Pls + (boff ^ sw)) = f2bf(acc[m][n][r] * inv);
      }
    }
  }
  // no __syncthreads(): P rows are wave-private; lgkmcnt orders same-wave LDS
  unsigned short* Cb = ctxT + ((size_t)b * HW + pix0 + w * 32) * 256;
#pragma unroll
  for (int half = 0; half < 2; half++) {
    f32x4 acc2[2][8];
#pragma unroll
    for (int m = 0; m < 2; m++)
#pragma unroll
      for (int n = 0; n < 8; n++) acc2[m][n] = zero;
    for (int ks = 0; ks < 5; ks++) {
      bf16x8 aP[2];
#pragma unroll
      for (int m = 0; m < 2; m++) {
        const int row = w * 32 + m * 16 + lr;
        unsigned boff = (unsigned)row * 320 + (unsigned)(ks * 64 + lg * 16);
        aP[m] = *(const bf16x8*)((const char*)Pls + (boff ^ ((unsigned)(row & 7) << 4)));
      }
      __builtin_amdgcn_s_setprio(1);
#pragma unroll
      for (int n = 0; n < 8; n++) {
        const int ch = half * 128 + n * 16 + lr;
        bf16x8 bV = *(const bf16x8*)(Vb + (size_t)ch * 160 + ks * 32 + lg * 8);
        acc2[0][n] = MFMA_16x16x32(aP[0], bV, acc2[0][n]);
        acc2[1][n] = MFMA_16x16x32(aP[1], bV, acc2[1][n]);
      }
      __builtin_amdgcn_s_setprio(0);
    }
#pragma unroll
    for (int m = 0; m < 2; m++)
#pragma unroll
      for (int n = 0; n < 8; n++)
#pragma unroll
        for (int r = 0; r < 4; r++)
          Cb[(size_t)(m * 16 + lg * 4 + r) * 256 + half * 128 + n * 16 + lr] =
              f2bf(acc2[m][n][r]);
  }
}

// ---------------- host launcher ----------------
extern "C" void kernel_launch(void* const* d_in, const int* in_sizes, int n_in,
                              void* d_out, int out_size, void* d_ws, size_t ws_size,
                              hipStream_t stream) {
  (void)in_sizes; (void)n_in; (void)out_size;
  const float* x     = (const float*)d_in[0];
  const float* proxy = (const float*)d_in[1];
  const float* w_fp1 = (const float*)d_in[2];
  const float* b_fp1 = (const float*)d_in[3];
  const float* w_fp2 = (const float*)d_in[4];
  const float* b_fp2 = (const float*)d_in[5];
  const float* w_fo1 = (const float*)d_in[6];
  const float* b_fo1 = (const float*)d_in[7];
  const float* w_fo2 = (const float*)d_in[8];
  const float* b_fo2 = (const float*)d_in[9];
  const float* w_fd  = (const float*)d_in[10];
  const float* b_fd  = (const float*)d_in[11];
  const float* w_fu  = (const float*)d_in[12];
  const float* b_fu  = (const float*)d_in[13];

  char* ws = (char*)d_ws;
  unsigned short* W1b  = (unsigned short*)(ws + 0);          // 256x512 bf16
  unsigned short* W2b  = (unsigned short*)(ws + 262144);     // 256x256
  unsigned short* Wub  = (unsigned short*)(ws + 393216);     // 512x256
  unsigned short* keyT = (unsigned short*)(ws + 655360);     // [8][160][256]
  unsigned short* Vv   = (unsigned short*)(ws + 1310720);    // [8][256][160]
  unsigned short* bufA = (unsigned short*)(ws + 2097152);    // q2T
  unsigned short* bufB = (unsigned short*)(ws + 2097152 + 134217728);  // q1T, later ctxT
  if (ws_size < 203423744) return;

  dim3 blk(256);
  kv_kernel<<<dim3(20, 8), blk, 0, stream>>>(proxy, w_fo1, b_fo1, w_fo2, b_fo2,
                                             w_fd, b_fd, keyT, Vv,
                                             w_fp1, w_fp2, w_fu, W1b, W2b, Wub);
  gemm1_fused<<<dim3(256, 8), blk, 0, stream>>>(x, W1b, b_fp1, bufB);
  gemm_bt_relu<0, 0, 1, 256><<<2048, blk, 0, stream>>>(
      bufB, W2b, b_fp2, bufA, 16384, 256,
      (long long)16384 * 256, 0, (long long)16384 * 256);
  attn_kernel<<<dim3(128, 8), blk, 0, stream>>>(bufA, keyT, Vv, bufB);
  gemm_bt_relu<1, 1, 2, 256><<<4096, blk, 0, stream>>>(
      Wub, bufB, b_fu, d_out, 512, 16384,
      0, (long long)16384 * 256, (long long)512 * 16384);
}